// Round 2
// baseline (557.250 us; speedup 1.0000x reference)
//
#include <hip/hip_runtime.h>
#include <hip/hip_bf16.h>
#include <math.h>

#define BB 2
#define CC 128
#define HH 96
#define WW 96
#define HWX (HH*WW)        // 9216
#define KTOT (CC*9)        // 1152
#define OC 128
#define ROWE 1168          // 1152 + 16 pad elements

typedef __attribute__((ext_vector_type(8))) __bf16 bf16x8;

// ---------------- K0: transpose conv_w (O,K) -> (K,O) fp32 for coalesced GEMM reads ----
__global__ __launch_bounds__(256) void wt_kernel(const float* __restrict__ w,
                                                 float* __restrict__ wt)
{
    int t = blockIdx.x * 256 + threadIdx.x;   // 0..147455
    int o = t & 127;
    int k = t >> 7;
    wt[t] = w[o * KTOT + k];                  // wt[k*128 + o]
}

// ---------------- K1: fused offset(18ch) + modulation(3ch) 3x3 conv (UNCHANGED) --------
__global__ __launch_bounds__(256) void offsets_kernel(
    const float* __restrict__ x, const float* __restrict__ pw,
    const float* __restrict__ pb, const float* __restrict__ aw,
    const float* __restrict__ ab, float* __restrict__ offw, float* __restrict__ adw)
{
    __shared__ float xs[12800];   // [c][10][10]
    int blk = blockIdx.x;         // b*144 + ti*12 + tj
    int b = blk / 144;
    int t2 = blk % 144;
    int ti = t2 / 12, tj = t2 % 12;
    int i0 = ti * 8, j0 = tj * 8;
    int tid = threadIdx.x;

    for (int idx = tid; idx < 12800; idx += 256) {
        int c = idx / 100; int r = idx % 100; int u = r / 10, v = r % 10;
        int gi = i0 + u - 1, gj = j0 + v - 1;
        float val = 0.f;
        if (gi >= 0 && gi < HH && gj >= 0 && gj < WW)
            val = x[((b * CC + c) * HH + gi) * WW + gj];
        xs[idx] = val;
    }
    __syncthreads();

    int wave = tid >> 6, lane = tid & 63;
    int pi = lane >> 3, pj = lane & 7;
    float acc[21];
#pragma unroll
    for (int o = 0; o < 21; ++o) acc[o] = 0.f;

    for (int cc = 0; cc < 32; ++cc) {
        int c = wave * 32 + cc;
        const float* xr = &xs[c * 100 + pi * 10 + pj];
#pragma unroll
        for (int di = 0; di < 3; ++di) {
#pragma unroll
            for (int dj = 0; dj < 3; ++dj) {
                float xv = xr[di * 10 + dj];
                int widx = c * 9 + di * 3 + dj;
#pragma unroll
                for (int o = 0; o < 18; ++o) acc[o] += pw[o * KTOT + widx] * xv;
#pragma unroll
                for (int o = 0; o < 3; ++o) acc[18 + o] += aw[o * KTOT + widx] * xv;
            }
        }
    }
    __syncthreads();
    if (wave > 0) {
        float* red = &xs[((wave - 1) * 64 + lane) * 21];
#pragma unroll
        for (int o = 0; o < 21; ++o) red[o] = acc[o];
    }
    __syncthreads();
    if (wave == 0) {
#pragma unroll
        for (int r = 0; r < 3; ++r) {
            const float* red = &xs[(r * 64 + lane) * 21];
#pragma unroll
            for (int o = 0; o < 21; ++o) acc[o] += red[o];
        }
        int i = i0 + pi, j = j0 + pj;
#pragma unroll
        for (int o = 0; o < 18; ++o)
            offw[((b * 18 + o) * HH + i) * WW + j] = acc[o] + pb[o];
#pragma unroll
        for (int o = 0; o < 3; ++o) {
            float z = acc[18 + o] + ab[o];
            adw[((b * 3 + o) * HH + i) * WW + j] = 2.f * (1.f - 1.f / (1.f + expf(-z)));
        }
    }
}

// ---------------- K2: bilinear sampling (UNCHANGED) + fp32 VALU implicit GEMM ----------
__global__ __launch_bounds__(256) void deform_kernel(
    const float* __restrict__ x, const float* __restrict__ offw,
    const float* __restrict__ adw, const float* __restrict__ wt,
    float* __restrict__ out)
{
    __shared__ __align__(16) __bf16 xoff[16 * ROWE];
    __shared__ int4   qidx[144];
    __shared__ float4 gwt[144];

    int tid = threadIdx.x;
    int gid0 = blockIdx.x * 16;
    int b  = gid0 / HWX;
    int r0 = gid0 - b * HWX;
    int i  = r0 / WW;
    int j0 = r0 % WW;

    if (tid < 144) {
        int px = tid / 9, n = tid % 9;
        int j = j0 + px;
        float offx = offw[((b * 18 + n) * HH + i) * WW + j];
        float offy = offw[((b * 18 + 9 + n) * HH + i) * WW + j];
        float ad   = adw[((b * 3 + (n % 3)) * HH + i) * WW + j];
        float pnx = (float)(n / 3 - 1), pny = (float)(n % 3 - 1);
        float pxf = (float)(i + 1) + pnx * (1.f + ad) + offx;
        float pyf = (float)(j + 1) + pny * (1.f + ad) + offy;
        float flx = floorf(pxf), fly = floorf(pyf);
        float qltx = fminf(fmaxf(flx, 0.f), 97.f);
        float qlty = fminf(fmaxf(fly, 0.f), 97.f);
        float qrbx = fminf(fmaxf(flx + 1.f, 0.f), 97.f);
        float qrby = fminf(fmaxf(fly + 1.f, 0.f), 97.f);
        bool mx = (pxf < 1.f) || (pxf > 96.f);
        bool my = (pyf < 1.f) || (pyf > 96.f);
        float pxm = mx ? flx : pxf; pxm = fminf(fmaxf(pxm, 0.f), 97.f);
        float pym = my ? fly : pyf; pym = fminf(fmaxf(pym, 0.f), 97.f);
        float glt = (1.f + (qltx - pxm)) * (1.f + (qlty - pym));
        float grb = (1.f - (qrbx - pxm)) * (1.f - (qrby - pym));
        float glb = (1.f + (qltx - pxm)) * (1.f - (qrby - pym));
        float grt = (1.f - (qrbx - pxm)) * (1.f + (qlty - pym));
        qidx[tid] = make_int4((int)qltx, (int)qlty, (int)qrbx, (int)qrby);
        gwt[tid]  = make_float4(glt, grb, glb, grt);
    }
    __syncthreads();

    const float* xb = x + (size_t)b * CC * HWX;
    for (int t = tid; t < 16 * KTOT; t += 256) {
        int px = t & 15;
        int rest = t >> 4;          // 0..1151
        int n = rest >> 7;          // 0..8
        int c = rest & 127;
        int pidx = px * 9 + n;
        int4 q = qidx[pidx];
        float4 g = gwt[pidx];
        const float* xc = xb + c * HWX;
        bool rx_lt = (q.x >= 1) & (q.x <= 96);
        bool rx_rb = (q.z >= 1) & (q.z <= 96);
        bool cy_lt = (q.y >= 1) & (q.y <= 96);
        bool cy_rb = (q.w >= 1) & (q.w <= 96);
        float vlt = (rx_lt && cy_lt) ? xc[(q.x - 1) * WW + (q.y - 1)] : 0.f;
        float vrb = (rx_rb && cy_rb) ? xc[(q.z - 1) * WW + (q.w - 1)] : 0.f;
        float vlb = (rx_lt && cy_rb) ? xc[(q.x - 1) * WW + (q.w - 1)] : 0.f;
        float vrt = (rx_rb && cy_lt) ? xc[(q.z - 1) * WW + (q.y - 1)] : 0.f;
        float val = g.x * vlt + g.y * vrb + g.z * vlb + g.w * vrt;
        xoff[px * ROWE + c * 9 + n] = (__bf16)val;
    }
    __syncthreads();

    // fp32 VALU GEMM: thread = (pixel m = tid&15, channel-chunk oc = tid>>4, 8 o's each)
    int m  = tid & 15;
    int oc = tid >> 4;
    const __bf16* arow = &xoff[m * ROWE];
    const float* wrow = wt + oc * 8;
    float acc[8];
#pragma unroll
    for (int jj = 0; jj < 8; ++jj) acc[jj] = 0.f;

#pragma unroll 4
    for (int k = 0; k < KTOT; ++k) {
        float xv = (float)arow[k];
        float4 wa = *(const float4*)(wrow + (size_t)k * 128);
        float4 wb = *(const float4*)(wrow + (size_t)k * 128 + 4);
        acc[0] += xv * wa.x;  acc[1] += xv * wa.y;
        acc[2] += xv * wa.z;  acc[3] += xv * wa.w;
        acc[4] += xv * wb.x;  acc[5] += xv * wb.y;
        acc[6] += xv * wb.z;  acc[7] += xv * wb.w;
    }

    int o0 = oc * 8;
#pragma unroll
    for (int jj = 0; jj < 8; ++jj)
        out[((b * OC + o0 + jj) * HH + i) * WW + (j0 + m)] = acc[jj];
}

extern "C" void kernel_launch(void* const* d_in, const int* in_sizes, int n_in,
                              void* d_out, int out_size, void* d_ws, size_t ws_size,
                              hipStream_t stream)
{
    const float* x  = (const float*)d_in[0];
    const float* cw = (const float*)d_in[1];   // conv_w  (128,128,3,3)
    const float* pw = (const float*)d_in[2];   // pconv_w (18,128,3,3)
    const float* pb = (const float*)d_in[3];   // pconv_b (18)
    const float* aw = (const float*)d_in[4];   // adconv_w (3,128,3,3)
    const float* ab = (const float*)d_in[5];   // adconv_b (3)
    float* out = (float*)d_out;

    char* ws = (char*)d_ws;
    float* offw = (float*)ws;                       // 2*18*9216 fp32
    float* adw  = offw + BB * 18 * HWX;             // 2*3*9216 fp32
    float* wtp  = adw + BB * 3 * HWX;               // 1152*128 fp32 (k-major)

    wt_kernel<<<(KTOT * OC) / 256, 256, 0, stream>>>(cw, wtp);
    offsets_kernel<<<BB * 144, 256, 0, stream>>>(x, pw, pb, aw, ab, offw, adw);
    deform_kernel<<<(BB * HWX) / 16, 256, 0, stream>>>(x, offw, adw, wtp, out);
}